// Round 2
// baseline (71.144 us; speedup 1.0000x reference)
//
#include <hip/hip_runtime.h>

// -------- gate primitives on a 16-amplitude register-resident state --------
// Flattened index: idx = b0*8 + b1*4 + b2*2 + b3  (qubit q -> bit (3-q))
template<int Q>
__device__ __forceinline__ void apply_ry(float (&sr)[16], float (&si)[16], float c, float s) {
    constexpr int m = 1 << (3 - Q);
    #pragma unroll
    for (int idx = 0; idx < 16; ++idx) {
        if (!(idx & m)) {
            const int j = idx | m;
            float ar = sr[idx], ai = si[idx], br = sr[j], bi = si[j];
            sr[idx] = c * ar - s * br;  si[idx] = c * ai - s * bi;
            sr[j]   = s * ar + c * br;  si[j]   = s * ai + c * bi;
        }
    }
}
// RZ(theta): bit0 amp *= (c - i s), bit1 amp *= (c + i s)   [c,s of theta/2]
template<int Q>
__device__ __forceinline__ void apply_rz(float (&sr)[16], float (&si)[16], float c, float s) {
    constexpr int m = 1 << (3 - Q);
    #pragma unroll
    for (int idx = 0; idx < 16; ++idx) {
        float r = sr[idx], i_ = si[idx];
        if (idx & m) { sr[idx] = c * r - s * i_;  si[idx] = c * i_ + s * r; }
        else         { sr[idx] = c * r + s * i_;  si[idx] = c * i_ - s * r; }
    }
}
template<int C, int T>
__device__ __forceinline__ void apply_cnot(float (&sr)[16], float (&si)[16]) {
    constexpr int mc = 1 << (3 - C), mt = 1 << (3 - T);
    #pragma unroll
    for (int idx = 0; idx < 16; ++idx) {
        if ((idx & mc) && !(idx & mt)) {
            const int j = idx | mt;
            float tr = sr[idx], ti = si[idx];
            sr[idx] = sr[j];  si[idx] = si[j];
            sr[j] = tr;       si[j] = ti;
        }
    }
}

// -------- precompute per-gate trig (params are batch-uniform) --------
// layout: trig[(l*4+i)*4 + {0,1,2,3}] = {cos(ry/2), sin(ry/2), cos(rz/2), sin(rz/2)}
__global__ void trig_kernel(const float* __restrict__ params, float* __restrict__ trig) {
    int j = threadIdx.x;            // gate index l*4+i, 12 gates
    if (j >= 12) return;
    float th_ry = params[j * 3 + 0];
    float th_rz = params[j * 3 + 1];
    float cy, sy, cz, sz;
    sincosf(0.5f * th_ry, &sy, &cy);
    sincosf(0.5f * th_rz, &sz, &cz);
    trig[j * 4 + 0] = cy;  trig[j * 4 + 1] = sy;
    trig[j * 4 + 2] = cz;  trig[j * 4 + 3] = sz;
}

// -------- main per-batch-element simulator --------
template<bool USE_TRIG>
__global__ __launch_bounds__(256) void qsim_kernel(const float* __restrict__ x,
                                                   const float* __restrict__ trig,
                                                   const float* __restrict__ params,
                                                   float* __restrict__ out, int n) {
    int b = blockIdx.x * blockDim.x + threadIdx.x;
    if (b >= n) return;

    // one 16B load for the 4 f32 angles
    float4 xr = reinterpret_cast<const float4*>(x)[b];
    float c0, s0, c1, s1, c2, s2, c3, s3;
    __sincosf(0.5f * xr.x, &s0, &c0);
    __sincosf(0.5f * xr.y, &s1, &c1);
    __sincosf(0.5f * xr.z, &s2, &c2);
    __sincosf(0.5f * xr.w, &s3, &c3);

    // encoded state = real product state
    float p01[4] = {c0 * c1, c0 * s1, s0 * c1, s0 * s1};
    float p23[4] = {c2 * c3, c2 * s3, s2 * c3, s2 * s3};
    float sr[16], si[16];
    #pragma unroll
    for (int i = 0; i < 16; ++i) { sr[i] = p01[i >> 2] * p23[i & 3]; si[i] = 0.0f; }

    #pragma unroll
    for (int l = 0; l < 3; ++l) {
        float t[16];
        if (USE_TRIG) {
            #pragma unroll
            for (int k = 0; k < 16; ++k) t[k] = trig[l * 16 + k];
        } else {
            #pragma unroll
            for (int i = 0; i < 4; ++i) {
                float th_ry = params[(l * 4 + i) * 3 + 0];
                float th_rz = params[(l * 4 + i) * 3 + 1];
                __sincosf(0.5f * th_ry, &t[i * 4 + 1], &t[i * 4 + 0]);
                __sincosf(0.5f * th_rz, &t[i * 4 + 3], &t[i * 4 + 2]);
            }
        }
        apply_ry<0>(sr, si, t[0],  t[1]);   apply_rz<0>(sr, si, t[2],  t[3]);
        apply_ry<1>(sr, si, t[4],  t[5]);   apply_rz<1>(sr, si, t[6],  t[7]);
        apply_ry<2>(sr, si, t[8],  t[9]);   apply_rz<2>(sr, si, t[10], t[11]);
        apply_ry<3>(sr, si, t[12], t[13]);  apply_rz<3>(sr, si, t[14], t[15]);
        apply_cnot<0, 1>(sr, si);
        apply_cnot<1, 2>(sr, si);
        apply_cnot<2, 3>(sr, si);
    }

    // <Z_q>: signed sums of probabilities; qubit q mask = 1<<(3-q)
    float z0 = 0.f, z1 = 0.f, z2 = 0.f, z3 = 0.f;
    #pragma unroll
    for (int i = 0; i < 16; ++i) {
        float p = sr[i] * sr[i] + si[i] * si[i];
        z0 += (i & 8) ? -p : p;
        z1 += (i & 4) ? -p : p;
        z2 += (i & 2) ? -p : p;
        z3 += (i & 1) ? -p : p;
    }

    float4 o;
    o.x = z0;  o.y = z1;  o.z = z2;  o.w = z3;
    reinterpret_cast<float4*>(out)[b] = o;
}

extern "C" void kernel_launch(void* const* d_in, const int* in_sizes, int n_in,
                              void* d_out, int out_size, void* d_ws, size_t ws_size,
                              hipStream_t stream) {
    const float* x      = (const float*)d_in[0];   // (B,4) f32
    const float* params = (const float*)d_in[1];   // (3,4,3) f32
    float* out          = (float*)d_out;           // (B,4) f32
    int n = in_sizes[0] / 4;
    int blocks = (n + 255) / 256;

    if (ws_size >= 48 * sizeof(float)) {
        float* trig = (float*)d_ws;
        hipLaunchKernelGGL(trig_kernel, dim3(1), dim3(64), 0, stream, params, trig);
        hipLaunchKernelGGL((qsim_kernel<true>), dim3(blocks), dim3(256), 0, stream,
                           x, trig, params, out, n);
    } else {
        hipLaunchKernelGGL((qsim_kernel<false>), dim3(blocks), dim3(256), 0, stream,
                           x, (const float*)nullptr, params, out, n);
    }
}

// Round 3
// 62.391 us; speedup vs baseline: 1.1403x; 1.1403x over previous
//
#include <hip/hip_runtime.h>

// Flattened state index: idx = b0*8 + b1*4 + b2*2 + b3  (qubit q -> bit (3-q))
template<int Q>
__device__ __forceinline__ void apply_ry(float (&sr)[16], float (&si)[16], float c, float s) {
    constexpr int m = 1 << (3 - Q);
    #pragma unroll
    for (int idx = 0; idx < 16; ++idx) {
        if (!(idx & m)) {
            const int j = idx | m;
            float ar = sr[idx], ai = si[idx], br = sr[j], bi = si[j];
            sr[idx] = c * ar - s * br;  si[idx] = c * ai - s * bi;
            sr[j]   = s * ar + c * br;  si[j]   = s * ai + c * bi;
        }
    }
}
// RZ(theta): bit==0 amp *= (c - i s), bit==1 amp *= (c + i s)   [c,s of theta/2]
template<int Q>
__device__ __forceinline__ void apply_rz(float (&sr)[16], float (&si)[16], float c, float s) {
    constexpr int m = 1 << (3 - Q);
    #pragma unroll
    for (int idx = 0; idx < 16; ++idx) {
        float r = sr[idx], i_ = si[idx];
        if (idx & m) { sr[idx] = c * r - s * i_;  si[idx] = c * i_ + s * r; }
        else         { sr[idx] = c * r + s * i_;  si[idx] = c * i_ - s * r; }
    }
}
template<int C, int T>
__device__ __forceinline__ void apply_cnot(float (&sr)[16], float (&si)[16]) {
    constexpr int mc = 1 << (3 - C), mt = 1 << (3 - T);
    #pragma unroll
    for (int idx = 0; idx < 16; ++idx) {
        if ((idx & mc) && !(idx & mt)) {
            const int j = idx | mt;
            float tr = sr[idx], ti = si[idx];
            sr[idx] = sr[j];  si[idx] = si[j];
            sr[j] = tr;       si[j] = ti;
        }
    }
}

__global__ __launch_bounds__(256) void qsim_kernel(const float* __restrict__ x,
                                                   const float* __restrict__ params,
                                                   float* __restrict__ out, int n) {
    int b = blockIdx.x * blockDim.x + threadIdx.x;
    if (b >= n) return;

    // ---- uniform (batch-independent) trig; compiler scalarizes the loads ----
    // params[l*12 + i*3 + {0:ry, 1:rz, 2:unused}]
    float cf[4], sf[4];          // layer-1 RZ, FULL angle (global phase factored out)
    float c1y[4], s1y[4];        // layer-2 RY half-angle
    float c1z[4], s1z[4];        // layer-2 RZ half-angle
    float c2y[4], s2y[4];        // layer-3 RY half-angle (layer-3 RZ dropped: phases
                                 // before pure permutations + |amp|^2 are unobservable)
    #pragma unroll
    for (int i = 0; i < 4; ++i) {
        __sincosf(params[0 * 12 + i * 3 + 1],        &sf[i],  &cf[i]);
        __sincosf(0.5f * params[1 * 12 + i * 3 + 0], &s1y[i], &c1y[i]);
        __sincosf(0.5f * params[1 * 12 + i * 3 + 1], &s1z[i], &c1z[i]);
        __sincosf(0.5f * params[2 * 12 + i * 3 + 0], &s2y[i], &c2y[i]);
    }

    // ---- layer 1: RY(x_i + theta_ry) merged with encoding; RZ as per-qubit phase ----
    // qubit i post-layer-1 vector (global phase e^{+i phi/2} dropped):
    //   v0 = cos(a_i)            (real)
    //   v1 = sin(a_i) * e^{i phi_i}
    float4 xr = reinterpret_cast<const float4*>(x)[b];
    float cy[4], sy[4];
    __sincosf(0.5f * (xr.x + params[0 * 12 + 0 * 3 + 0]), &sy[0], &cy[0]);
    __sincosf(0.5f * (xr.y + params[0 * 12 + 1 * 3 + 0]), &sy[1], &cy[1]);
    __sincosf(0.5f * (xr.z + params[0 * 12 + 2 * 3 + 0]), &sy[2], &cy[2]);
    __sincosf(0.5f * (xr.w + params[0 * 12 + 3 * 3 + 0]), &sy[3], &cy[3]);
    float v1r[4], v1i[4];
    #pragma unroll
    for (int i = 0; i < 4; ++i) { v1r[i] = sy[i] * cf[i]; v1i[i] = sy[i] * sf[i]; }

    // pair tensor products: P = q0 (x) q1, Q = q2 (x) q3   (component 0 of each qubit real)
    float pr[4], pi_[4], qr[4], qi[4];
    pr[0] = cy[0] * cy[1];                          pi_[0] = 0.0f;
    pr[1] = cy[0] * v1r[1];                         pi_[1] = cy[0] * v1i[1];
    pr[2] = v1r[0] * cy[1];                         pi_[2] = v1i[0] * cy[1];
    pr[3] = v1r[0] * v1r[1] - v1i[0] * v1i[1];      pi_[3] = v1r[0] * v1i[1] + v1i[0] * v1r[1];
    qr[0] = cy[2] * cy[3];                          qi[0] = 0.0f;
    qr[1] = cy[2] * v1r[3];                         qi[1] = cy[2] * v1i[3];
    qr[2] = v1r[2] * cy[3];                         qi[2] = v1i[2] * cy[3];
    qr[3] = v1r[2] * v1r[3] - v1i[2] * v1i[3];      qi[3] = v1r[2] * v1i[3] + v1i[2] * v1r[3];

    // full state after layer-1 single-qubit gates: state[p*4+q] = P[p] * Q[q]
    float sr[16], si[16];
    #pragma unroll
    for (int p = 0; p < 4; ++p)
        #pragma unroll
        for (int q = 0; q < 4; ++q) {
            sr[p * 4 + q] = pr[p] * qr[q] - pi_[p] * qi[q];
            si[p * 4 + q] = pr[p] * qi[q] + pi_[p] * qr[q];
        }

    // layer-1 CNOT chain
    apply_cnot<0, 1>(sr, si);
    apply_cnot<1, 2>(sr, si);
    apply_cnot<2, 3>(sr, si);

    // ---- layer 2: full RY + RZ on each qubit, then CNOT chain ----
    apply_ry<0>(sr, si, c1y[0], s1y[0]);  apply_rz<0>(sr, si, c1z[0], s1z[0]);
    apply_ry<1>(sr, si, c1y[1], s1y[1]);  apply_rz<1>(sr, si, c1z[1], s1z[1]);
    apply_ry<2>(sr, si, c1y[2], s1y[2]);  apply_rz<2>(sr, si, c1z[2], s1z[2]);
    apply_ry<3>(sr, si, c1y[3], s1y[3]);  apply_rz<3>(sr, si, c1z[3], s1z[3]);
    apply_cnot<0, 1>(sr, si);
    apply_cnot<1, 2>(sr, si);
    apply_cnot<2, 3>(sr, si);

    // ---- layer 3: RY only (RZ unobservable), CNOT chain ----
    apply_ry<0>(sr, si, c2y[0], s2y[0]);
    apply_ry<1>(sr, si, c2y[1], s2y[1]);
    apply_ry<2>(sr, si, c2y[2], s2y[2]);
    apply_ry<3>(sr, si, c2y[3], s2y[3]);
    apply_cnot<0, 1>(sr, si);
    apply_cnot<1, 2>(sr, si);
    apply_cnot<2, 3>(sr, si);

    // ---- <Z_q> via tree-structured signed sums ----
    float p16[16];
    #pragma unroll
    for (int i = 0; i < 16; ++i) p16[i] = sr[i] * sr[i] + si[i] * si[i];
    float s8[8], d8[8];
    #pragma unroll
    for (int i = 0; i < 8; ++i) { s8[i] = p16[2 * i] + p16[2 * i + 1];
                                  d8[i] = p16[2 * i] - p16[2 * i + 1]; }
    float z3 = (d8[0] + d8[1]) + (d8[2] + d8[3]) + ((d8[4] + d8[5]) + (d8[6] + d8[7]));
    float z2 = (s8[0] - s8[1]) + (s8[2] - s8[3]) + ((s8[4] - s8[5]) + (s8[6] - s8[7]));
    float t4[4];
    #pragma unroll
    for (int i = 0; i < 4; ++i) t4[i] = s8[2 * i] + s8[2 * i + 1];
    float z1 = (t4[0] - t4[1]) + (t4[2] - t4[3]);
    float z0 = (t4[0] + t4[1]) - (t4[2] + t4[3]);

    float4 o;  o.x = z0;  o.y = z1;  o.z = z2;  o.w = z3;
    reinterpret_cast<float4*>(out)[b] = o;
}

extern "C" void kernel_launch(void* const* d_in, const int* in_sizes, int n_in,
                              void* d_out, int out_size, void* d_ws, size_t ws_size,
                              hipStream_t stream) {
    const float* x      = (const float*)d_in[0];   // (B,4) f32
    const float* params = (const float*)d_in[1];   // (3,4,3) f32
    float* out          = (float*)d_out;           // (B,4) f32
    int n = in_sizes[0] / 4;
    int blocks = (n + 255) / 256;
    hipLaunchKernelGGL(qsim_kernel, dim3(blocks), dim3(256), 0, stream, x, params, out, n);
}